// Round 5
// baseline (392.594 us; speedup 1.0000x reference)
//
#include <hip/hip_runtime.h>

#define D 128
#define S 16

// Fused KGCN v4 (resubmit — round-4 failure was container-level infra, not
// the kernel; audited: no spill, no divergent barriers, no OOB, no
// data-dependent loops).
//
// 8 elements/block, 256 threads, grid 1024 -> 4 blocks/CU, 16 waves/CU.
//
// Why 4 blocks/CU: phase 2 is DS-pipe-bound (~2048 broadcast ds_read_b128
// per CU x ~12cyc ~= 10us) while phase 1 is HBM-gather-bound (~15us).
// At 2 blocks/CU both resident blocks move through phases in near-lockstep
// so the two costs ADD; at 4 blocks/CU staggered blocks overlap phase-2 DS
// under phase-1 gather stalls. Per-block tails also shrink 2x.
//
// VGPR discipline: round-0's chunked gather body (load 8 rel rows ->
// scores; twice; softmax; load 8 ent rows -> msg; twice) peaks at ~75 live
// VGPRs, so __launch_bounds__(256,4)'s 128-cap cannot spill. (The round-3
// issue-early variant holds r4+n4a+n4b ~= 130 live and would spill at this
// occupancy -- deliberately NOT used; 16 waves/CU of TLP hides the chunk
// latency instead.)
//
// Phase 2 (two relu((msg+rep)@W+b) layers): 2-row x 2-col register tile
// (M=4 W-reuse, 256 MB total W traffic — same as v3). Group g = (gc=g&1,
// gr=g>>1): rows gr*2..+1, cols gc*64 + ln*2. Both half-waves of a wave
// share gr -> xv LDS reads are wave-uniform broadcasts (free bank-wise).
// Cross-wave WAR on the x1/rep2 overwrites handled by __syncthreads().
//
// FP op order identical to the round-0/1/3 passing kernels everywhere
// (scores 4-local dot + 5-step xor tree, chunked s-ascending msg, softmax,
// d-ascending matmul acc, msg+y, final dot tree) -> absmax stays 0.
__global__ __launch_bounds__(256, 4) void kgcn_fused(
    const int* __restrict__ u, const int* __restrict__ v,
    const int* __restrict__ adj_ent, const int* __restrict__ adj_rel,
    const float* __restrict__ usr, const float* __restrict__ ent,
    const float* __restrict__ rel, const float* __restrict__ W,
    const float* __restrict__ bias, float* __restrict__ out)
{
    __shared__ float sX[8 * D];      // 4 KB: x0 rows, then x1, then rep2
    __shared__ float sMsg[8 * D];    // 4 KB: msg rows

    const int tid = threadIdx.x;
    const int g   = tid >> 5;        // 8 groups, one element each
    const int ln  = tid & 31;
    const int b   = blockIdx.x * 8 + g;

    const int uu = u[b];
    const int vv = v[b];

    const float4 u4   = *(const float4*)(usr + (size_t)uu * D + ln * 4);
    const float4 rep0 = *(const float4*)(ent + (size_t)vv * D + ln * 4);

    // lanes 0..15 hold the adjacency row; shuffled out per s
    const int ae = adj_ent[(size_t)vv * S + (ln & 15)];
    const int ar = adj_rel[(size_t)vv * S + (ln & 15)];

    // ---- scores, chunked 2x8 (round-0 body: ~75 live VGPRs peak) --------
    float sc[S];
    #pragma unroll
    for (int h = 0; h < 2; ++h) {
        float4 r4[8];
        #pragma unroll
        for (int s = 0; s < 8; ++s) {
            const int nr = __shfl(ar, h * 8 + s, 32);
            r4[s] = *(const float4*)(rel + (size_t)nr * D + ln * 4);
        }
        #pragma unroll
        for (int s = 0; s < 8; ++s) {
            float p = u4.x * r4[s].x + u4.y * r4[s].y +
                      u4.z * r4[s].z + u4.w * r4[s].w;
            #pragma unroll
            for (int off = 16; off >= 1; off >>= 1) p += __shfl_xor(p, off, 32);
            sc[h * 8 + s] = p;
        }
    }

    // ---- softmax over S=16 (same op order as passing kernels) -----------
    float mx = sc[0];
    #pragma unroll
    for (int s = 1; s < S; ++s) mx = fmaxf(mx, sc[s]);
    float sum = 0.f;
    #pragma unroll
    for (int s = 0; s < S; ++s) { sc[s] = __expf(sc[s] - mx); sum += sc[s]; }
    const float inv = 1.f / sum;

    // ---- msg, chunked 2x8 ------------------------------------------------
    float m0 = 0.f, m1 = 0.f, m2 = 0.f, m3 = 0.f;
    #pragma unroll
    for (int h = 0; h < 2; ++h) {
        float4 n4[8];
        #pragma unroll
        for (int s = 0; s < 8; ++s) {
            const int ne = __shfl(ae, h * 8 + s, 32);
            n4[s] = *(const float4*)(ent + (size_t)ne * D + ln * 4);
        }
        #pragma unroll
        for (int s = 0; s < 8; ++s) {
            const float a = sc[h * 8 + s] * inv;
            m0 += a * n4[s].x; m1 += a * n4[s].y;
            m2 += a * n4[s].z; m3 += a * n4[s].w;
        }
    }

    *(float4*)&sMsg[g * D + ln * 4] = make_float4(m0, m1, m2, m3);
    *(float4*)&sX[g * D + ln * 4] =
        make_float4(m0 + rep0.x, m1 + rep0.y, m2 + rep0.z, m3 + rep0.w);
    __syncthreads();

    // ---------------- phase 2: two layers, 2-row x 2-col register tile ---
    const int gc  = g & 1;           // column half
    const int gr  = g >> 1;          // row pair
    const int m0r = gr * 2;
    const int j0  = gc * 64 + ln * 2;
    const float2 b2 = *(const float2*)(bias + j0);

    float y[2][2];

    {   // ---- layer 1: y = relu(x0 @ W + b) ----
        float acc[2][2];
        acc[0][0] = acc[0][1] = acc[1][0] = acc[1][1] = 0.f;

        #pragma unroll 4
        for (int d0 = 0; d0 < D; d0 += 4) {
            float4 xv[2];
            #pragma unroll
            for (int k = 0; k < 2; ++k)
                xv[k] = *(const float4*)&sX[(m0r + k) * D + d0];  // wave-uniform
            #pragma unroll
            for (int dd = 0; dd < 4; ++dd) {
                const float2 w2 = *(const float2*)(W + (d0 + dd) * D + j0);
                #pragma unroll
                for (int k = 0; k < 2; ++k) {
                    const float xm = dd == 0 ? xv[k].x : dd == 1 ? xv[k].y
                                   : dd == 2 ? xv[k].z : xv[k].w;
                    acc[k][0] += xm * w2.x; acc[k][1] += xm * w2.y;
                }
            }
        }
        #pragma unroll
        for (int k = 0; k < 2; ++k) {
            y[k][0] = fmaxf(acc[k][0] + b2.x, 0.f);
            y[k][1] = fmaxf(acc[k][1] + b2.y, 0.f);
        }
    }
    __syncthreads();   // all x0 reads done before x1 overwrite (cross-wave WAR)

    // x1 = msg + y
    #pragma unroll
    for (int k = 0; k < 2; ++k) {
        const float2 mg2 = *(const float2*)&sMsg[(m0r + k) * D + j0];
        *(float2*)&sX[(m0r + k) * D + j0] =
            make_float2(mg2.x + y[k][0], mg2.y + y[k][1]);
    }
    __syncthreads();

    {   // ---- layer 2: rep2 = relu(x1 @ W + b) ----
        float acc[2][2];
        acc[0][0] = acc[0][1] = acc[1][0] = acc[1][1] = 0.f;

        #pragma unroll 4
        for (int d0 = 0; d0 < D; d0 += 4) {
            float4 xv[2];
            #pragma unroll
            for (int k = 0; k < 2; ++k)
                xv[k] = *(const float4*)&sX[(m0r + k) * D + d0];
            #pragma unroll
            for (int dd = 0; dd < 4; ++dd) {
                const float2 w2 = *(const float2*)(W + (d0 + dd) * D + j0);
                #pragma unroll
                for (int k = 0; k < 2; ++k) {
                    const float xm = dd == 0 ? xv[k].x : dd == 1 ? xv[k].y
                                   : dd == 2 ? xv[k].z : xv[k].w;
                    acc[k][0] += xm * w2.x; acc[k][1] += xm * w2.y;
                }
            }
        }
        #pragma unroll
        for (int k = 0; k < 2; ++k) {
            y[k][0] = fmaxf(acc[k][0] + b2.x, 0.f);
            y[k][1] = fmaxf(acc[k][1] + b2.y, 0.f);
        }
    }
    __syncthreads();   // all x1 reads done before rep2 overwrite

    #pragma unroll
    for (int k = 0; k < 2; ++k)
        *(float2*)&sX[(m0r + k) * D + j0] = make_float2(y[k][0], y[k][1]);
    __syncthreads();

    // ---------------- phase 3: out = sigmoid(u . rep2) --------------------
    {
        const float4 rf = *(const float4*)&sX[g * D + ln * 4];
        float pr = u4.x * rf.x + u4.y * rf.y + u4.z * rf.z + u4.w * rf.w;
        #pragma unroll
        for (int off = 16; off >= 1; off >>= 1) pr += __shfl_xor(pr, off, 32);
        if (ln == 0) out[b] = 1.f / (1.f + __expf(-pr));
    }
}

extern "C" void kernel_launch(void* const* d_in, const int* in_sizes, int n_in,
                              void* d_out, int out_size, void* d_ws, size_t ws_size,
                              hipStream_t stream)
{
    const int* u       = (const int*)d_in[0];
    const int* v       = (const int*)d_in[1];
    const int* adj_ent = (const int*)d_in[2];
    const int* adj_rel = (const int*)d_in[3];
    const float* usr   = (const float*)d_in[4];
    const float* ent   = (const float*)d_in[5];
    const float* rel   = (const float*)d_in[6];
    const float* W     = (const float*)d_in[7];
    const float* bias  = (const float*)d_in[8];
    float* out = (float*)d_out;

    hipLaunchKernelGGL(kgcn_fused, dim3(8192 / 8), dim3(256), 0, stream,
                       u, v, adj_ent, adj_rel, usr, ent, rel, W, bias, out);
}

// Round 6
// 376.451 us; speedup vs baseline: 1.0429x; 1.0429x over previous
//
#include <hip/hip_runtime.h>

#define D 128
#define S 16

// Fused KGCN v5: attack the COLD gather latency (round-5 profile: v4 ran at
// 294 GB/s = ~1 outstanding 512B row per CU, VGPR_Count=64 because
// __launch_bounds__(256,4) made the compiler serialize the load bursts).
//
// Changes vs v4:
//  1. __launch_bounds__(256) only — no min-waves hint. Compiler free to
//     allocate ~170 VGPRs and keep the full gather burst in flight.
//  2. ALL 17 random ent-table rows (rep0 + 16 neighbors) issued in ONE
//     early burst (~16 KB/group, ~32 KB/wave outstanding), consumed only
//     after rel-loads + scores + softmax (~700+ cyc of L1-fed work) —
//     one HBM latency round per element instead of two-plus.
//  3. Phase 2 reverts to v3's exact M=4 tile (4 rows x 2 cols/lane),
//     groups 0..3 only (groups 4..7 idle at barriers): per-element W
//     traffic (32 KB) and DS instruction count identical to the measured
//     376-us v3 config.
//
// 8 elements/block, 256 threads, grid 1024. Expect ~3 blocks/CU at
// ~170 VGPR -> 12 waves/CU, each wave with up to 32 KB of gathers in
// flight -> Little's law satisfied (need ~9 KB/CU for HBM saturation).
//
// FP op order identical to the round-0/1/3 passing kernels everywhere
// (scores 4-local dot + 5-step xor tree, s-ascending msg accumulation,
// softmax, d-ascending matmul acc, msg+y, final dot tree) -> absmax 0.
__global__ __launch_bounds__(256) void kgcn_fused(
    const int* __restrict__ u, const int* __restrict__ v,
    const int* __restrict__ adj_ent, const int* __restrict__ adj_rel,
    const float* __restrict__ usr, const float* __restrict__ ent,
    const float* __restrict__ rel, const float* __restrict__ W,
    const float* __restrict__ bias, float* __restrict__ out)
{
    __shared__ float sX[8 * D];      // 4 KB: x0 rows, then x1, then rep2
    __shared__ float sMsg[8 * D];    // 4 KB: msg rows

    const int tid = threadIdx.x;
    const int g   = tid >> 5;        // 8 groups, one element each
    const int ln  = tid & 31;
    const int b   = blockIdx.x * 8 + g;

    const int uu = u[b];
    const int vv = v[b];

    // lanes 0..15 hold the adjacency row; shuffled out per s
    const int ae = adj_ent[(size_t)vv * S + (ln & 15)];
    const int ar = adj_rel[(size_t)vv * S + (ln & 15)];

    // ---- EARLY BURST: all random ent-table rows for this element --------
    const float4 rep0 = *(const float4*)(ent + (size_t)vv * D + ln * 4);
    float4 n4[S];
    #pragma unroll
    for (int s = 0; s < S; ++s) {
        const int ne = __shfl(ae, s, 32);
        n4[s] = *(const float4*)(ent + (size_t)ne * D + ln * 4);
    }

    // u row (usr table 51 MB — mostly cached, cheap) and rel rows (32 KB
    // table, L1-resident): short-latency work that hides the ent burst.
    const float4 u4 = *(const float4*)(usr + (size_t)uu * D + ln * 4);

    float sc[S];
    #pragma unroll
    for (int h = 0; h < 2; ++h) {
        float4 r4[8];
        #pragma unroll
        for (int s = 0; s < 8; ++s) {
            const int nr = __shfl(ar, h * 8 + s, 32);
            r4[s] = *(const float4*)(rel + (size_t)nr * D + ln * 4);
        }
        #pragma unroll
        for (int s = 0; s < 8; ++s) {
            float p = u4.x * r4[s].x + u4.y * r4[s].y +
                      u4.z * r4[s].z + u4.w * r4[s].w;
            #pragma unroll
            for (int off = 16; off >= 1; off >>= 1) p += __shfl_xor(p, off, 32);
            sc[h * 8 + s] = p;
        }
    }

    // ---- softmax over S=16 (same op order as passing kernels) -----------
    float mx = sc[0];
    #pragma unroll
    for (int s = 1; s < S; ++s) mx = fmaxf(mx, sc[s]);
    float sum = 0.f;
    #pragma unroll
    for (int s = 0; s < S; ++s) { sc[s] = __expf(sc[s] - mx); sum += sc[s]; }
    const float inv = 1.f / sum;

    // ---- msg: consume the burst, s ascending (bit-exact vs chunked) -----
    float m0 = 0.f, m1 = 0.f, m2 = 0.f, m3 = 0.f;
    #pragma unroll
    for (int s = 0; s < S; ++s) {
        const float a = sc[s] * inv;
        m0 += a * n4[s].x; m1 += a * n4[s].y;
        m2 += a * n4[s].z; m3 += a * n4[s].w;
    }

    *(float4*)&sMsg[g * D + ln * 4] = make_float4(m0, m1, m2, m3);
    *(float4*)&sX[g * D + ln * 4] =
        make_float4(m0 + rep0.x, m1 + rep0.y, m2 + rep0.z, m3 + rep0.w);
    __syncthreads();

    // ---------------- phase 2: v3's 4-row x 2-col tile, groups 0..3 ------
    const int gc  = g & 1;           // column half
    const int gr  = g >> 1;          // row quad (0..1 used)
    const int m0r = gr * 4;
    const int j0  = gc * 64 + ln * 2;

    float y[4][2];

    if (g < 4) {   // ---- layer 1: y = relu(x0 @ W + b) ----
        const float2 b2 = *(const float2*)(bias + j0);
        float acc[4][2];
        #pragma unroll
        for (int k = 0; k < 4; ++k) { acc[k][0] = 0.f; acc[k][1] = 0.f; }

        #pragma unroll 4
        for (int d0 = 0; d0 < D; d0 += 4) {
            float4 xv[4];
            #pragma unroll
            for (int k = 0; k < 4; ++k)
                xv[k] = *(const float4*)&sX[(m0r + k) * D + d0];
            #pragma unroll
            for (int dd = 0; dd < 4; ++dd) {
                const float2 w2 = *(const float2*)(W + (d0 + dd) * D + j0);
                #pragma unroll
                for (int k = 0; k < 4; ++k) {
                    const float xm = dd == 0 ? xv[k].x : dd == 1 ? xv[k].y
                                   : dd == 2 ? xv[k].z : xv[k].w;
                    acc[k][0] += xm * w2.x; acc[k][1] += xm * w2.y;
                }
            }
        }
        #pragma unroll
        for (int k = 0; k < 4; ++k) {
            y[k][0] = fmaxf(acc[k][0] + b2.x, 0.f);
            y[k][1] = fmaxf(acc[k][1] + b2.y, 0.f);
        }
    }
    __syncthreads();   // all x0 reads done before x1 overwrite (cross-wave WAR)

    if (g < 4) {       // x1 = msg + y
        #pragma unroll
        for (int k = 0; k < 4; ++k) {
            const float2 mg2 = *(const float2*)&sMsg[(m0r + k) * D + j0];
            *(float2*)&sX[(m0r + k) * D + j0] =
                make_float2(mg2.x + y[k][0], mg2.y + y[k][1]);
        }
    }
    __syncthreads();

    if (g < 4) {   // ---- layer 2: rep2 = relu(x1 @ W + b) ----
        const float2 b2 = *(const float2*)(bias + j0);
        float acc[4][2];
        #pragma unroll
        for (int k = 0; k < 4; ++k) { acc[k][0] = 0.f; acc[k][1] = 0.f; }

        #pragma unroll 4
        for (int d0 = 0; d0 < D; d0 += 4) {
            float4 xv[4];
            #pragma unroll
            for (int k = 0; k < 4; ++k)
                xv[k] = *(const float4*)&sX[(m0r + k) * D + d0];
            #pragma unroll
            for (int dd = 0; dd < 4; ++dd) {
                const float2 w2 = *(const float2*)(W + (d0 + dd) * D + j0);
                #pragma unroll
                for (int k = 0; k < 4; ++k) {
                    const float xm = dd == 0 ? xv[k].x : dd == 1 ? xv[k].y
                                   : dd == 2 ? xv[k].z : xv[k].w;
                    acc[k][0] += xm * w2.x; acc[k][1] += xm * w2.y;
                }
            }
        }
        #pragma unroll
        for (int k = 0; k < 4; ++k) {
            y[k][0] = fmaxf(acc[k][0] + b2.x, 0.f);
            y[k][1] = fmaxf(acc[k][1] + b2.y, 0.f);
        }
    }
    __syncthreads();   // all x1 reads done before rep2 overwrite

    if (g < 4) {
        #pragma unroll
        for (int k = 0; k < 4; ++k)
            *(float2*)&sX[(m0r + k) * D + j0] = make_float2(y[k][0], y[k][1]);
    }
    __syncthreads();

    // ---------------- phase 3: out = sigmoid(u . rep2) --------------------
    {
        const float4 rf = *(const float4*)&sX[g * D + ln * 4];
        float pr = u4.x * rf.x + u4.y * rf.y + u4.z * rf.z + u4.w * rf.w;
        #pragma unroll
        for (int off = 16; off >= 1; off >>= 1) pr += __shfl_xor(pr, off, 32);
        if (ln == 0) out[b] = 1.f / (1.f + __expf(-pr));
    }
}

extern "C" void kernel_launch(void* const* d_in, const int* in_sizes, int n_in,
                              void* d_out, int out_size, void* d_ws, size_t ws_size,
                              hipStream_t stream)
{
    const int* u       = (const int*)d_in[0];
    const int* v       = (const int*)d_in[1];
    const int* adj_ent = (const int*)d_in[2];
    const int* adj_rel = (const int*)d_in[3];
    const float* usr   = (const float*)d_in[4];
    const float* ent   = (const float*)d_in[5];
    const float* rel   = (const float*)d_in[6];
    const float* W     = (const float*)d_in[7];
    const float* bias  = (const float*)d_in[8];
    float* out = (float*)d_out;

    hipLaunchKernelGGL(kgcn_fused, dim3(8192 / 8), dim3(256), 0, stream,
                       u, v, adj_ent, adj_rel, usr, ent, rel, W, bias, out);
}